// Round 16
// baseline (166.637 us; speedup 1.0000x reference)
//
#include <hip/hip_runtime.h>

#define T_STEPS 20
#define BATCH   65536
#define HIDN    64
#define GATES   256
#define CHUNKS  2        // two 32-row chunks per WG -> 1024 WGs = 4/CU resident
#define HSTR    72       // hl row stride (bf16); 144B keeps b128 alignment, breaks pow2

typedef __bf16 bf16x8 __attribute__((ext_vector_type(8)));
typedef float  f32x4  __attribute__((ext_vector_type(4)));
typedef float  f32x2  __attribute__((ext_vector_type(2)));
typedef unsigned int uint32;
typedef uint32 uint32x4 __attribute__((ext_vector_type(4)));

#define L2E 1.4426950408889634f

#if __has_builtin(__builtin_amdgcn_exp2f)
#define EXP2F(x) __builtin_amdgcn_exp2f(x)
#else
#define EXP2F(x) exp2f(x)
#endif
#if __has_builtin(__builtin_amdgcn_rcpf)
#define RCPF(x) __builtin_amdgcn_rcpf(x)
#else
#define RCPF(x) (1.0f / (x))
#endif

__device__ __forceinline__ uint32 pack2bf16(float a, float b) {
    unsigned short ua = __builtin_bit_cast(unsigned short, (__bf16)a);
    unsigned short ub = __builtin_bit_cast(unsigned short, (__bf16)b);
    return (uint32)ua | ((uint32)ub << 16);
}

// R15 base (packed-f32 act, 103.7us) + x-MFMA SOFTWARE PIPELINE:
// the 8 x/bias MFMAs per step don't depend on h, so they are issued one
// step EARLY into a second accumulator set (A/B ping-pong, explicitly
// 2-step-unrolled loop so all acc indexing is compile-time — runtime
// indexing would go to scratch). Post-barrier critical path shrinks
// 24 -> 16 MFMAs, and the x-MFMA issue overlaps the previous step's
// activation VALU (MFMA and VALU pipes run concurrently on CDNA4).
// Unified reg tally ~120/128 at the 4-wave tier (tripwire: FETCH balloon
// = spill = revert). waves_per_eu(4,4) per R5/R7/R10 lesson.
__global__ __launch_bounds__(256)
__attribute__((amdgpu_waves_per_eu(4, 4)))
void Encoder_6949257085628_kernel(const float* __restrict__ obs,
                                  const float* __restrict__ W_emb,
                                  const float* __restrict__ b_emb,
                                  const float* __restrict__ W_ih,
                                  const float* __restrict__ W_hh,
                                  const float* __restrict__ b_ih,
                                  const float* __restrict__ b_hh,
                                  float* __restrict__ out) {
    __shared__ float wcbc[GATES * 3];                    // 3 KB (scaled Wc,bc)
    __shared__ __align__(16) __bf16 hlb[2][32 * HSTR];   // 2 x 4.5 KB, dbuf

    const int tid  = threadIdx.x;
    const int jtw  = tid >> 6;       // wave index = hidden-quarter
    const int lane = tid & 63;
    const int q    = lane >> 4;      // 0..3 (K-group)
    const int c16  = lane & 15;
    const bool qz  = (q == 0);

    // ---- fold embedding into gate map with log2e scaling ----
    {
        int g = tid;  // exactly 256 threads
        float sf = ((g >> 6) == 2) ? (2.0f * L2E) : (-L2E);
        float a0 = 0.f, a1 = 0.f, ab = 0.f;
        for (int e = 0; e < 64; ++e) {
            float wie = W_ih[g * 64 + e];
            a0 = fmaf(wie, W_emb[e * 2 + 0], a0);
            a1 = fmaf(wie, W_emb[e * 2 + 1], a1);
            ab = fmaf(wie, b_emb[e], ab);
        }
        wcbc[g * 3 + 0] = a0 * sf;
        wcbc[g * 3 + 1] = a1 * sf;
        wcbc[g * 3 + 2] = (ab + b_ih[g] + b_hh[g]) * sf;
    }

    // ---- this wave's 8 W_hh B-fragments, scaled, in registers ----
    bf16x8 bfr[4][2];
    #pragma unroll
    for (int f = 0; f < 4; ++f) {
        const float sf = (f == 2) ? (2.0f * L2E) : (-L2E);
        const int rowW = f * 64 + jtw * 16 + c16;
        #pragma unroll
        for (int ks = 0; ks < 2; ++ks) {
            const float* p = W_hh + rowW * 64 + ks * 32 + q * 8;
            f32x4 lo = *(const f32x4*)p;
            f32x4 hi = *(const f32x4*)(p + 4);
            bf16x8 b;
            b[0] = (__bf16)(lo[0] * sf); b[1] = (__bf16)(lo[1] * sf);
            b[2] = (__bf16)(lo[2] * sf); b[3] = (__bf16)(lo[3] * sf);
            b[4] = (__bf16)(hi[0] * sf); b[5] = (__bf16)(hi[1] * sf);
            b[6] = (__bf16)(hi[2] * sf); b[7] = (__bf16)(hi[3] * sf);
            bfr[f][ks] = b;
        }
    }
    __syncthreads();   // wcbc staged

    // ---- x/bias B-frag words (per f): [w0,w1 | bc_hi,bc_lo | 0..], q==0 ----
    uint32 bxw0[4], bxw1[4];
    #pragma unroll
    for (int f = 0; f < 4; ++f) {
        int col = f * 64 + jtw * 16 + c16;
        float w0s = wcbc[col * 3 + 0];
        float w1s = wcbc[col * 3 + 1];
        float bcs = wcbc[col * 3 + 2];
        float blo = bcs - (float)((__bf16)bcs);
        bxw0[f] = qz ? pack2bf16(w0s, w1s) : 0u;
        bxw1[f] = qz ? pack2bf16(bcs, blo) : 0u;
    }
    const uint32 axw1 = qz ? 0x3F803F80u : 0u;   // [1.0,1.0] bf16, K-slots 2,3

    const int wgBase = blockIdx.x * (32 * CHUNKS);
    const int hOff   = jtw * 16 + c16;           // this lane's hidden index

    #pragma unroll 1
    for (int c = 0; c < CHUNKS; ++c) {
        const int rbw = wgBase + c * 32;
        __syncthreads();   // protects hlb reuse across chunks

        // c-state as row-pairs: cst[m][rp] covers rows {2rp, 2rp+1}
        f32x2 cst[2][2];
        #pragma unroll
        for (int m = 0; m < 2; ++m)
            #pragma unroll
            for (int rp = 0; rp < 2; ++rp) cst[m][rp] = f32x2{0.f, 0.f};

        f32x2  xc[2];            // x of row (m*16 + c16); q==0 lanes feed MFMA
        bf16x8 a0c[2], a1c[2];   // h A-frags, read right after each barrier
        f32x4  accA[2][4], accB[2][4];   // ping-pong accumulators

        auto loadx = [&](int t) {
            const float* ob = obs + (size_t)t * (BATCH * 2);
            #pragma unroll
            for (int m = 0; m < 2; ++m)
                xc[m] = *(const f32x2*)&ob[(size_t)(rbw + m * 16 + c16) * 2];
        };
        auto ax_of = [&](f32x2 xv) -> bf16x8 {
            uint32 w0 = qz ? pack2bf16(xv[0], xv[1]) : 0u;
            return __builtin_bit_cast(bf16x8, uint32x4{w0, axw1, 0u, 0u});
        };
        auto bx_of = [&](int f) -> bf16x8 {
            return __builtin_bit_cast(bf16x8, uint32x4{bxw0[f], bxw1[f], 0u, 0u});
        };
        auto xmfma = [&](f32x4 (&acc)[2][4]) {
            #pragma unroll
            for (int m = 0; m < 2; ++m) {
                bf16x8 ax = ax_of(xc[m]);
                #pragma unroll
                for (int f = 0; f < 4; ++f)
                    acc[m][f] = __builtin_amdgcn_mfma_f32_16x16x32_bf16(
                        ax, bx_of(f), f32x4{0.f, 0.f, 0.f, 0.f}, 0, 0, 0);
            }
        };
        auto hmfma = [&](f32x4 (&acc)[2][4]) {
            #pragma unroll
            for (int m = 0; m < 2; ++m)
                #pragma unroll
                for (int f = 0; f < 4; ++f) {
                    acc[m][f] = __builtin_amdgcn_mfma_f32_16x16x32_bf16(
                        a0c[m], bfr[f][0], acc[m][f], 0, 0, 0);
                    acc[m][f] = __builtin_amdgcn_mfma_f32_16x16x32_bf16(
                        a1c[m], bfr[f][1], acc[m][f], 0, 0, 0);
                }
        };
        auto readA = [&](const __bf16* hp) {
            #pragma unroll
            for (int m = 0; m < 2; ++m) {
                a0c[m] = *(const bf16x8*)&hp[(m * 16 + c16) * HSTR + q * 8];
                a1c[m] = *(const bf16x8*)&hp[(m * 16 + c16) * HSTR + 32 + q * 8];
            }
        };
        // 7-trans activation on row-pairs; elementwise math as f32x2 so the
        // backend forms v_pk_{add,mul,fma}_f32 (R15 win).
        auto act_store = [&](f32x4 (&acc)[4], int m, __bf16* hw, bool last) {
            #pragma unroll
            for (int rp = 0; rp < 2; ++rp) {
                const int r0 = 2 * rp, r1 = 2 * rp + 1;
                f32x2 A{EXP2F(acc[0][r0]), EXP2F(acc[0][r1])};   // e^{-x_i}
                f32x2 E{EXP2F(acc[1][r0]), EXP2F(acc[1][r1])};   // e^{-x_f}
                f32x2 B{EXP2F(acc[2][r0]), EXP2F(acc[2][r1])};   // e^{2 x_g}
                f32x2 C{EXP2F(acc[3][r0]), EXP2F(acc[3][r1])};   // e^{-x_o}
                f32x2 one{1.0f, 1.0f};
                f32x2 pA = A + one, pB = B + one, pE = E + one;
                f32x2 P  = pA * pB;
                f32x2 Bm = B - one;
                f32x2 num = __builtin_elementwise_fma(cst[m][rp], P, Bm * pE);
                f32x2 den = pE * P;
                f32x2 rd{RCPF(den[0]), RCPF(den[1])};
                f32x2 cc = num * rd;
                cst[m][rp] = cc;
                f32x2 ccs = cc * f32x2{2.0f * L2E, 2.0f * L2E};
                f32x2 D{EXP2F(ccs[0]), EXP2F(ccs[1])};           // e^{2c}
                f32x2 hn = D - one;
                f32x2 hd = (one + C) * (one + D);
                f32x2 rh{RCPF(hd[0]), RCPF(hd[1])};
                f32x2 h  = hn * rh;
                if (!last) {
                    hw[(m * 16 + q * 4 + r0) * HSTR + hOff] = (__bf16)h[0];
                    hw[(m * 16 + q * 4 + r1) * HSTR + hOff] = (__bf16)h[1];
                } else {
                    out[(size_t)(rbw + m * 16 + q * 4 + r0) * HIDN + hOff] = h[0];
                    out[(size_t)(rbw + m * 16 + q * 4 + r1) * HIDN + hOff] = h[1];
                }
            }
        };

        // ---- prologue: t = 0 (no h) ----
        loadx(0);
        xmfma(accA);                 // gates(0) = x/bias only
        loadx(1);
        xmfma(accB);                 // x-part of gates(1), ahead of time
        loadx(2);
        act_store(accA[0], 0, hlb[0], false);
        act_store(accA[1], 1, hlb[0], false);
        __syncthreads();
        readA(hlb[0]);

        // ---- t = 1..18 as 9 explicit pairs (all acc indexing static) ----
        // Invariant at top of step t: cur = bias + x(t); a-frags = h(t-1);
        // xc = x(t+1).
        #pragma unroll 1
        for (int tt = 1; tt < T_STEPS - 1; tt += 2) {
            // step t = tt (odd): cur=accB, nxt=accA, writes hlb[1]
            hmfma(accB);
            xmfma(accA);                         // uses xc = x(tt+1)
            loadx(tt + 2 < T_STEPS ? tt + 2 : T_STEPS - 1);
            act_store(accB[0], 0, hlb[1], false);
            act_store(accB[1], 1, hlb[1], false);
            __syncthreads();
            readA(hlb[1]);
            // step t = tt+1 (even): cur=accA, nxt=accB, writes hlb[0]
            hmfma(accA);
            xmfma(accB);                         // uses xc = x(tt+2)
            loadx(tt + 3 < T_STEPS ? tt + 3 : T_STEPS - 1);
            act_store(accA[0], 0, hlb[0], false);
            act_store(accA[1], 1, hlb[0], false);
            __syncthreads();
            readA(hlb[0]);
        }

        // ---- t = 19: cur = accB, write fp32 output ----
        hmfma(accB);
        act_store(accB[0], 0, nullptr, true);
        act_store(accB[1], 1, nullptr, true);
    }
}

extern "C" void kernel_launch(void* const* d_in, const int* in_sizes, int n_in,
                              void* d_out, int out_size, void* d_ws, size_t ws_size,
                              hipStream_t stream) {
    const float* obs   = (const float*)d_in[0];
    const float* W_emb = (const float*)d_in[1];
    const float* b_emb = (const float*)d_in[2];
    const float* W_ih  = (const float*)d_in[3];
    const float* W_hh  = (const float*)d_in[4];
    const float* b_ih  = (const float*)d_in[5];
    const float* b_hh  = (const float*)d_in[6];
    float* out = (float*)d_out;

    dim3 grid(BATCH / (32 * CHUNKS));  // 1024 WGs = 4 per CU, all resident
    dim3 block(256);
    Encoder_6949257085628_kernel<<<grid, block, 0, stream>>>(
        obs, W_emb, b_emb, W_ih, W_hh, b_ih, b_hh, out);
}

// Round 17
// 103.983 us; speedup vs baseline: 1.6025x; 1.6025x over previous
//
#include <hip/hip_runtime.h>

#define T_STEPS 20
#define BATCH   65536
#define HIDN    64
#define GATES   256
#define CHUNKS  2        // two 32-row chunks per WG -> 1024 WGs = 4/CU resident
#define HSTR    72       // hl row stride (bf16); 144B keeps b128 alignment, breaks pow2

typedef __bf16 bf16x8 __attribute__((ext_vector_type(8)));
typedef float  f32x4  __attribute__((ext_vector_type(4)));
typedef float  f32x2  __attribute__((ext_vector_type(2)));
typedef unsigned int uint32;
typedef uint32 uint32x4 __attribute__((ext_vector_type(4)));

#define L2E 1.4426950408889634f

#if __has_builtin(__builtin_amdgcn_exp2f)
#define EXP2F(x) __builtin_amdgcn_exp2f(x)
#else
#define EXP2F(x) exp2f(x)
#endif
#if __has_builtin(__builtin_amdgcn_rcpf)
#define RCPF(x) __builtin_amdgcn_rcpf(x)
#else
#define RCPF(x) (1.0f / (x))
#endif

__device__ __forceinline__ uint32 pack2bf16(float a, float b) {
    unsigned short ua = __builtin_bit_cast(unsigned short, (__bf16)a);
    unsigned short ub = __builtin_bit_cast(unsigned short, (__bf16)b);
    return (uint32)ua | ((uint32)ub << 16);
}

// R15 RESTORED EXACTLY (verified best: 103.7us). Structure:
//  - WG = 4 waves, 32 rows as 2 independent 16-row m-blocks per wave;
//    wave jtw owns hidden quarter, 8 scaled W_hh B-frags register-resident.
//  - x-contribution AND bias via one MFMA per (m,f): A=[x0,x1,1,1,0..],
//    B=[w0,w1,bc_hi,bc_lo,0..], C-in = 0.
//  - log2e folded into all staged weights (i,f,o: -L2E ; g: +2*L2E).
//  - 7-trans activation (5 exp2 + 2 shared rcp) on row-pairs as f32x2 so
//    the backend forms v_pk_{add,mul,fma}_f32 (R15's -4.6%).
//  - h through dbuf LDS, one barrier/step; 1024 WGs = 4/CU.
// Closed doors (measured): 8-wave tier at codegen (R5/R10: clamp+spill),
// >=120-reg structures (R2/R7/R16: spill), occupancy/stagger/setprio/
// residency probes (R12-R14: neutral). Issue floor reached at this tier.
__global__ __launch_bounds__(256)
__attribute__((amdgpu_waves_per_eu(4, 4)))
void Encoder_6949257085628_kernel(const float* __restrict__ obs,
                                  const float* __restrict__ W_emb,
                                  const float* __restrict__ b_emb,
                                  const float* __restrict__ W_ih,
                                  const float* __restrict__ W_hh,
                                  const float* __restrict__ b_ih,
                                  const float* __restrict__ b_hh,
                                  float* __restrict__ out) {
    __shared__ float wcbc[GATES * 3];                    // 3 KB (scaled Wc,bc)
    __shared__ __align__(16) __bf16 hlb[2][32 * HSTR];   // 2 x 4.5 KB, dbuf

    const int tid  = threadIdx.x;
    const int jtw  = tid >> 6;       // wave index = hidden-quarter
    const int lane = tid & 63;
    const int q    = lane >> 4;      // 0..3 (K-group)
    const int c16  = lane & 15;
    const bool qz  = (q == 0);

    // ---- fold embedding into gate map with log2e scaling ----
    {
        int g = tid;  // exactly 256 threads
        float sf = ((g >> 6) == 2) ? (2.0f * L2E) : (-L2E);
        float a0 = 0.f, a1 = 0.f, ab = 0.f;
        for (int e = 0; e < 64; ++e) {
            float wie = W_ih[g * 64 + e];
            a0 = fmaf(wie, W_emb[e * 2 + 0], a0);
            a1 = fmaf(wie, W_emb[e * 2 + 1], a1);
            ab = fmaf(wie, b_emb[e], ab);
        }
        wcbc[g * 3 + 0] = a0 * sf;
        wcbc[g * 3 + 1] = a1 * sf;
        wcbc[g * 3 + 2] = (ab + b_ih[g] + b_hh[g]) * sf;
    }

    // ---- this wave's 8 W_hh B-fragments, scaled, in registers ----
    bf16x8 bfr[4][2];
    #pragma unroll
    for (int f = 0; f < 4; ++f) {
        const float sf = (f == 2) ? (2.0f * L2E) : (-L2E);
        const int rowW = f * 64 + jtw * 16 + c16;
        #pragma unroll
        for (int ks = 0; ks < 2; ++ks) {
            const float* p = W_hh + rowW * 64 + ks * 32 + q * 8;
            f32x4 lo = *(const f32x4*)p;
            f32x4 hi = *(const f32x4*)(p + 4);
            bf16x8 b;
            b[0] = (__bf16)(lo[0] * sf); b[1] = (__bf16)(lo[1] * sf);
            b[2] = (__bf16)(lo[2] * sf); b[3] = (__bf16)(lo[3] * sf);
            b[4] = (__bf16)(hi[0] * sf); b[5] = (__bf16)(hi[1] * sf);
            b[6] = (__bf16)(hi[2] * sf); b[7] = (__bf16)(hi[3] * sf);
            bfr[f][ks] = b;
        }
    }
    __syncthreads();   // wcbc staged

    // ---- x/bias B-frag words (per f): [w0,w1 | bc_hi,bc_lo | 0..], q==0 ----
    uint32 bxw0[4], bxw1[4];
    #pragma unroll
    for (int f = 0; f < 4; ++f) {
        int col = f * 64 + jtw * 16 + c16;
        float w0s = wcbc[col * 3 + 0];
        float w1s = wcbc[col * 3 + 1];
        float bcs = wcbc[col * 3 + 2];
        float blo = bcs - (float)((__bf16)bcs);
        bxw0[f] = qz ? pack2bf16(w0s, w1s) : 0u;
        bxw1[f] = qz ? pack2bf16(bcs, blo) : 0u;
    }
    const uint32 axw1 = qz ? 0x3F803F80u : 0u;   // [1.0,1.0] bf16, K-slots 2,3

    const int wgBase = blockIdx.x * (32 * CHUNKS);
    const int hOff   = jtw * 16 + c16;           // this lane's hidden index

    #pragma unroll 1
    for (int c = 0; c < CHUNKS; ++c) {
        const int rbw = wgBase + c * 32;
        __syncthreads();   // protects hlb reuse across chunks

        // c-state as row-pairs: cst[m][rp] covers rows {2rp, 2rp+1}
        f32x2 cst[2][2];
        #pragma unroll
        for (int m = 0; m < 2; ++m)
            #pragma unroll
            for (int rp = 0; rp < 2; ++rp) cst[m][rp] = f32x2{0.f, 0.f};

        // lane tracks x of row (m*16 + c16); only q==0 lanes feed the MFMA
        f32x2 xc[2];
        #pragma unroll
        for (int m = 0; m < 2; ++m)
            xc[m] = *(const f32x2*)&obs[(size_t)(rbw + m * 16 + c16) * 2];

        auto ax_of = [&](f32x2 xv) -> bf16x8 {
            uint32 w0 = qz ? pack2bf16(xv[0], xv[1]) : 0u;
            return __builtin_bit_cast(bf16x8, uint32x4{w0, axw1, 0u, 0u});
        };
        auto bx_of = [&](int f) -> bf16x8 {
            return __builtin_bit_cast(bf16x8, uint32x4{bxw0[f], bxw1[f], 0u, 0u});
        };
        // 7-trans activation on row-pairs; elementwise math as f32x2 so the
        // backend can form v_pk_{add,mul,fma}_f32.
        auto act_store = [&](f32x4 (&acc)[4], int m, __bf16* hw, bool last) {
            #pragma unroll
            for (int rp = 0; rp < 2; ++rp) {
                const int r0 = 2 * rp, r1 = 2 * rp + 1;
                f32x2 A{EXP2F(acc[0][r0]), EXP2F(acc[0][r1])};   // e^{-x_i}
                f32x2 E{EXP2F(acc[1][r0]), EXP2F(acc[1][r1])};   // e^{-x_f}
                f32x2 B{EXP2F(acc[2][r0]), EXP2F(acc[2][r1])};   // e^{2 x_g}
                f32x2 C{EXP2F(acc[3][r0]), EXP2F(acc[3][r1])};   // e^{-x_o}
                f32x2 one{1.0f, 1.0f};
                f32x2 pA = A + one, pB = B + one, pE = E + one;
                f32x2 P  = pA * pB;
                f32x2 Bm = B - one;
                f32x2 num = __builtin_elementwise_fma(cst[m][rp], P, Bm * pE);
                f32x2 den = pE * P;
                f32x2 rd{RCPF(den[0]), RCPF(den[1])};
                f32x2 cc = num * rd;
                cst[m][rp] = cc;
                f32x2 ccs = cc * f32x2{2.0f * L2E, 2.0f * L2E};
                f32x2 D{EXP2F(ccs[0]), EXP2F(ccs[1])};           // e^{2c}
                f32x2 hn = D - one;
                f32x2 hd = (one + C) * (one + D);
                f32x2 rh{RCPF(hd[0]), RCPF(hd[1])};
                f32x2 h  = hn * rh;
                if (!last) {
                    hw[(m * 16 + q * 4 + r0) * HSTR + hOff] = (__bf16)h[0];
                    hw[(m * 16 + q * 4 + r1) * HSTR + hOff] = (__bf16)h[1];
                } else {
                    out[(size_t)(rbw + m * 16 + q * 4 + r0) * HIDN + hOff] = h[0];
                    out[(size_t)(rbw + m * 16 + q * 4 + r1) * HIDN + hOff] = h[1];
                }
            }
        };

        bf16x8 a0c[2], a1c[2];   // h A-frags, read right after each barrier

        // ---- t = 0 (no h): gates = x/bias MFMA only ----
        {
            f32x4 acc[2][4];
            #pragma unroll
            for (int m = 0; m < 2; ++m) {
                bf16x8 ax = ax_of(xc[m]);
                #pragma unroll
                for (int f = 0; f < 4; ++f)
                    acc[m][f] = __builtin_amdgcn_mfma_f32_16x16x32_bf16(
                        ax, bx_of(f), f32x4{0.f, 0.f, 0.f, 0.f}, 0, 0, 0);
            }
            #pragma unroll
            for (int m = 0; m < 2; ++m)
                xc[m] = *(const f32x2*)&obs[(size_t)(BATCH * 2) + (size_t)(rbw + m * 16 + c16) * 2];
            act_store(acc[0], 0, hlb[0], false);
            act_store(acc[1], 1, hlb[0], false);
            __syncthreads();
            #pragma unroll
            for (int m = 0; m < 2; ++m) {
                a0c[m] = *(const bf16x8*)&hlb[0][(m * 16 + c16) * HSTR + q * 8];
                a1c[m] = *(const bf16x8*)&hlb[0][(m * 16 + c16) * HSTR + 32 + q * 8];
            }
        }

        // ---- t = 1..18, branch-free ----
        #pragma unroll 1
        for (int t = 1; t < T_STEPS - 1; ++t) {
            f32x4 acc[2][4];
            #pragma unroll
            for (int m = 0; m < 2; ++m) {
                bf16x8 ax = ax_of(xc[m]);
                #pragma unroll
                for (int f = 0; f < 4; ++f) {
                    acc[m][f] = __builtin_amdgcn_mfma_f32_16x16x32_bf16(
                        ax, bx_of(f), f32x4{0.f, 0.f, 0.f, 0.f}, 0, 0, 0);
                    acc[m][f] = __builtin_amdgcn_mfma_f32_16x16x32_bf16(
                        a0c[m], bfr[f][0], acc[m][f], 0, 0, 0);
                    acc[m][f] = __builtin_amdgcn_mfma_f32_16x16x32_bf16(
                        a1c[m], bfr[f][1], acc[m][f], 0, 0, 0);
                }
            }
            #pragma unroll
            for (int m = 0; m < 2; ++m)
                xc[m] = *(const f32x2*)&obs[(size_t)(t + 1) * (BATCH * 2) + (size_t)(rbw + m * 16 + c16) * 2];
            act_store(acc[0], 0, hlb[t & 1], false);
            act_store(acc[1], 1, hlb[t & 1], false);
            __syncthreads();
            #pragma unroll
            for (int m = 0; m < 2; ++m) {
                a0c[m] = *(const bf16x8*)&hlb[t & 1][(m * 16 + c16) * HSTR + q * 8];
                a1c[m] = *(const bf16x8*)&hlb[t & 1][(m * 16 + c16) * HSTR + 32 + q * 8];
            }
        }

        // ---- t = 19: write fp32 output ----
        {
            f32x4 acc[2][4];
            #pragma unroll
            for (int m = 0; m < 2; ++m) {
                bf16x8 ax = ax_of(xc[m]);
                #pragma unroll
                for (int f = 0; f < 4; ++f) {
                    acc[m][f] = __builtin_amdgcn_mfma_f32_16x16x32_bf16(
                        ax, bx_of(f), f32x4{0.f, 0.f, 0.f, 0.f}, 0, 0, 0);
                    acc[m][f] = __builtin_amdgcn_mfma_f32_16x16x32_bf16(
                        a0c[m], bfr[f][0], acc[m][f], 0, 0, 0);
                    acc[m][f] = __builtin_amdgcn_mfma_f32_16x16x32_bf16(
                        a1c[m], bfr[f][1], acc[m][f], 0, 0, 0);
                }
            }
            act_store(acc[0], 0, nullptr, true);
            act_store(acc[1], 1, nullptr, true);
        }
    }
}

extern "C" void kernel_launch(void* const* d_in, const int* in_sizes, int n_in,
                              void* d_out, int out_size, void* d_ws, size_t ws_size,
                              hipStream_t stream) {
    const float* obs   = (const float*)d_in[0];
    const float* W_emb = (const float*)d_in[1];
    const float* b_emb = (const float*)d_in[2];
    const float* W_ih  = (const float*)d_in[3];
    const float* W_hh  = (const float*)d_in[4];
    const float* b_ih  = (const float*)d_in[5];
    const float* b_hh  = (const float*)d_in[6];
    float* out = (float*)d_out;

    dim3 grid(BATCH / (32 * CHUNKS));  // 1024 WGs = 4 per CU, all resident
    dim3 block(256);
    Encoder_6949257085628_kernel<<<grid, block, 0, stream>>>(
        obs, W_emb, b_emb, W_ih, W_hh, b_ih, b_hh, out);
}